// Round 1
// baseline (214.126 us; speedup 1.0000x reference)
//
#include <hip/hip_runtime.h>
#include <stdint.h>

#define N_AGENTS 4096
#define TOPK 12
#define EPSF 1e-4f

static __device__ __forceinline__ unsigned long long umin64(unsigned long long a,
                                                            unsigned long long b) {
    return a < b ? a : b;
}

// One block (256 threads) per agent row i. Each thread owns 16 candidates as
// packed (float_bits(d)<<32)|j, so u64-min == (smallest distance, lowest index)
// which exactly matches jax.lax.top_k(-d) stable ordering.
__global__ __launch_bounds__(256) void topk_kernel(const float* __restrict__ states,
                                                   int* __restrict__ idx_out,
                                                   float* __restrict__ dist_out) {
    const int i = blockIdx.x;
    const int t = threadIdx.x;
    const float xi = states[i * 4 + 0];
    const float yi = states[i * 4 + 1];

    unsigned long long loc[16];
#pragma unroll
    for (int s = 0; s < 16; ++s) {
        const int j = t + s * 256;
        const float dx = xi - states[j * 4 + 0];
        const float dy = yi - states[j * 4 + 1];
        // faithful to ref: sum of (square + EPS) over the 2 planar dims
        const float d2 = (dx * dx + EPSF) + (dy * dy + EPSF);
        const float d = sqrtf(d2);
        loc[s] = ((unsigned long long)__float_as_uint(d) << 32) | (unsigned int)j;
    }
    unsigned long long lmin = loc[0];
#pragma unroll
    for (int s = 1; s < 16; ++s) lmin = umin64(lmin, loc[s]);

    __shared__ unsigned long long red[4];
    __shared__ unsigned long long gmin_s;

    for (int r = 0; r < TOPK; ++r) {
        unsigned long long v = lmin;
#pragma unroll
        for (int off = 32; off >= 1; off >>= 1)
            v = umin64(v, __shfl_down(v, off, 64));
        if ((t & 63) == 0) red[t >> 6] = v;
        __syncthreads();
        if (t == 0) {
            unsigned long long g = umin64(umin64(red[0], red[1]), umin64(red[2], red[3]));
            gmin_s = g;
            idx_out[i * TOPK + r] = (int)(unsigned int)(g & 0xffffffffULL);
            dist_out[i * TOPK + r] = __uint_as_float((unsigned int)(g >> 32));
        }
        __syncthreads();
        const unsigned long long g = gmin_s;
        if (lmin == g) {
            // exactly one thread block-wide owns g (index bits are unique)
#pragma unroll
            for (int s = 0; s < 16; ++s)
                if (loc[s] == g) loc[s] = ~0ULL;
            lmin = loc[0];
#pragma unroll
            for (int s = 1; s < 16; ++s) lmin = umin64(lmin, loc[s]);
        }
        // no barrier needed here: next round's writes to red[] happen after
        // this round's sync2; gmin_s rewrite is after next round's sync1.
    }
}

// One thread per edge. All weight indices are wave-uniform -> scalar loads.
// Layer2 computed in 16-wide chunks fused into layer3 accumulation so we
// never hold all 128 h2 values live (register budget ~ h1[64]+h3[64]+h2c[16]).
__global__ __launch_bounds__(256) void mlp_kernel(
    const float* __restrict__ states,
    const int* __restrict__ idx_in,
    const float* __restrict__ dist_in,
    const float* __restrict__ W1, const float* __restrict__ b1,
    const float* __restrict__ W2, const float* __restrict__ b2,
    const float* __restrict__ W3, const float* __restrict__ b3,
    const float* __restrict__ W4, const float* __restrict__ b4,
    float* __restrict__ out) {
    const int e = blockIdx.x * 256 + threadIdx.x;  // < 4096*12
    const int i = e / TOPK;
    const int j = idx_in[e];
    const float d = dist_in[e];

    float feat[6];
#pragma unroll
    for (int c = 0; c < 4; ++c) feat[c] = states[i * 4 + c] - states[j * 4 + c];
    feat[4] = (i == j) ? 1.0f : 0.0f;
    feat[5] = d - 0.1f;

    float h1[64];
#pragma unroll
    for (int o = 0; o < 64; ++o) {
        float acc = b1[o];
#pragma unroll
        for (int f = 0; f < 6; ++f) acc += feat[f] * W1[f * 64 + o];
        h1[o] = fmaxf(acc, 0.0f);
    }

    float h3[64];
#pragma unroll
    for (int o = 0; o < 64; ++o) h3[o] = b3[o];

    for (int c = 0; c < 8; ++c) {  // 8 chunks of 16 layer-2 outputs
        float h2c[16];
#pragma unroll
        for (int o = 0; o < 16; ++o) h2c[o] = b2[c * 16 + o];
        for (int kk = 0; kk < 64; ++kk) {
            const float hk = h1[kk];
#pragma unroll
            for (int o = 0; o < 16; ++o) h2c[o] += hk * W2[kk * 128 + c * 16 + o];
        }
#pragma unroll
        for (int o = 0; o < 16; ++o) h2c[o] = fmaxf(h2c[o], 0.0f);
        for (int kk = 0; kk < 16; ++kk) {
            const float hv = h2c[kk];
#pragma unroll
            for (int o = 0; o < 64; ++o) h3[o] += hv * W3[(c * 16 + kk) * 64 + o];
        }
    }

    float acc = b4[0];
#pragma unroll
    for (int o = 0; o < 64; ++o) acc += fmaxf(h3[o], 0.0f) * W4[o];

    out[e] = (d <= 1.0f) ? acc : 0.0f;
}

extern "C" void kernel_launch(void* const* d_in, const int* in_sizes, int n_in,
                              void* d_out, int out_size, void* d_ws, size_t ws_size,
                              hipStream_t stream) {
    const float* states = (const float*)d_in[0];
    const float* W1 = (const float*)d_in[1];
    const float* b1 = (const float*)d_in[2];
    const float* W2 = (const float*)d_in[3];
    const float* b2 = (const float*)d_in[4];
    const float* W3 = (const float*)d_in[5];
    const float* b3 = (const float*)d_in[6];
    const float* W4 = (const float*)d_in[7];
    const float* b4 = (const float*)d_in[8];

    int* idx = (int*)d_ws;
    float* dist = (float*)((char*)d_ws + (size_t)N_AGENTS * TOPK * sizeof(int));

    topk_kernel<<<N_AGENTS, 256, 0, stream>>>(states, idx, dist);
    mlp_kernel<<<(N_AGENTS * TOPK) / 256, 256, 0, stream>>>(
        states, idx, dist, W1, b1, W2, b2, W3, b3, W4, b4, (float*)d_out);
}

// Round 2
// 158.916 us; speedup vs baseline: 1.3474x; 1.3474x over previous
//
#include <hip/hip_runtime.h>
#include <stdint.h>

#define N_AGENTS 4096
#define TOPK 12
#define EPSF 1e-4f

typedef unsigned long long u64;

static __device__ __forceinline__ u64 umin64(u64 a, u64 b) { return a < b ? a : b; }

// One block (256 threads = 4 waves) per agent row i.
// Phase 1: each wave reduces its 1024 candidates to a sorted top-12 via 12
// barrier-free butterfly min rounds (packed (dist_bits<<32)|j so u64-min ==
// jax.lax.top_k stable order). Phase 2: single barrier, wave 0 merges 4x12.
__global__ __launch_bounds__(256) void topk_kernel(const float* __restrict__ states,
                                                   int* __restrict__ idx_out,
                                                   float* __restrict__ dist_out) {
    const int i = blockIdx.x;
    const int t = threadIdx.x;
    const int lane = t & 63;
    const int wv = t >> 6;
    const float2* st2 = (const float2*)states;  // states row = 2 float2s; [j*2] = (x,y)
    const float2 me = st2[i * 2];

    u64 loc[16];
#pragma unroll
    for (int s = 0; s < 16; ++s) {
        const int j = t + s * 256;
        const float2 p = st2[j * 2];
        const float dx = me.x - p.x;
        const float dy = me.y - p.y;
        // faithful to ref rounding: (dx^2 + eps) + (dy^2 + eps)
        const float d2 = (dx * dx + EPSF) + (dy * dy + EPSF);
        const float d = sqrtf(d2);
        loc[s] = ((u64)__float_as_uint(d) << 32) | (unsigned int)j;
    }
    u64 lmin = loc[0];
#pragma unroll
    for (int s = 1; s < 16; ++s) lmin = umin64(lmin, loc[s]);

    __shared__ u64 cand[4 * TOPK];

    for (int r = 0; r < TOPK; ++r) {
        u64 v = lmin;
#pragma unroll
        for (int off = 1; off < 64; off <<= 1) v = umin64(v, __shfl_xor(v, off, 64));
        if (lane == 0) cand[wv * TOPK + r] = v;
        if (lmin == v) {  // exactly one lane owns v (unique index bits)
#pragma unroll
            for (int s = 0; s < 16; ++s)
                if (loc[s] == v) loc[s] = ~0ULL;
            lmin = loc[0];
#pragma unroll
            for (int s = 1; s < 16; ++s) lmin = umin64(lmin, loc[s]);
        }
    }
    __syncthreads();

    if (wv == 0) {
        u64 a = (lane < 4 * TOPK) ? cand[lane] : ~0ULL;
        for (int r = 0; r < TOPK; ++r) {
            u64 v = a;
#pragma unroll
            for (int off = 1; off < 64; off <<= 1) v = umin64(v, __shfl_xor(v, off, 64));
            if (lane == 0) {
                idx_out[i * TOPK + r] = (int)(unsigned int)(v & 0xffffffffULL);
                dist_out[i * TOPK + r] = __uint_as_float((unsigned int)(v >> 32));
            }
            if (a == v) a = ~0ULL;
        }
    }
}

// MLP: block = 256 threads (4 waves), 64 edges per block (edge = lane).
// Wave `sub` owns h2 output chunk [32*sub, 32*sub+32) and h3 output chunk
// [16*sub, 16*sub+16). Full h1 computed redundantly per wave (cheap, no comm).
// h2 exchanged via LDS [edge][128] with stride 132 (16B-aligned, bank-balanced)
// so layer-3 inner loop uses ds_read_b128. Weight indices are wave-uniform
// (sub via readfirstlane) -> scalar s_loads, freeing the VALU for FMAs.
__global__ __launch_bounds__(256) void mlp_kernel(
    const float* __restrict__ states,
    const int* __restrict__ idx_in,
    const float* __restrict__ dist_in,
    const float* __restrict__ W1, const float* __restrict__ b1,
    const float* __restrict__ W2, const float* __restrict__ b2,
    const float* __restrict__ W3, const float* __restrict__ b3,
    const float* __restrict__ W4, const float* __restrict__ b4,
    float* __restrict__ out) {
    __shared__ __align__(16) float lds_h2[64 * 132];
    __shared__ float pr[4 * 64];

    const int lane = threadIdx.x & 63;
    const int sub = __builtin_amdgcn_readfirstlane(threadIdx.x >> 6);
    const int e = blockIdx.x * 64 + lane;
    const int i = e / TOPK;
    const int j = idx_in[e];
    const float d = dist_in[e];

    float feat[6];
#pragma unroll
    for (int c = 0; c < 4; ++c) feat[c] = states[i * 4 + c] - states[j * 4 + c];
    feat[4] = (i == j) ? 1.0f : 0.0f;
    feat[5] = d - 0.1f;

    // layer 1: full 64 outputs per thread (redundant across waves, no comm)
    float h1[64];
#pragma unroll
    for (int o = 0; o < 64; ++o) {
        float acc = b1[o];
#pragma unroll
        for (int f = 0; f < 6; ++f) acc += feat[f] * W1[f * 64 + o];
        h1[o] = fmaxf(acc, 0.0f);
    }

    // layer 2: this wave's 32-output chunk, full k=64
    const int co = sub * 32;
    float h2c[32];
#pragma unroll
    for (int o = 0; o < 32; ++o) h2c[o] = b2[co + o];
    for (int k = 0; k < 64; ++k) {
        const float hk = h1[k];
#pragma unroll
        for (int o = 0; o < 32; ++o) h2c[o] += hk * W2[k * 128 + co + o];
    }
#pragma unroll
    for (int o = 0; o < 32; ++o) h2c[o] = fmaxf(h2c[o], 0.0f);

    // exchange h2 chunks: lds_h2[edge][k], stride 132 words (16B aligned)
    float4* dst = (float4*)&lds_h2[lane * 132 + co];
#pragma unroll
    for (int o4 = 0; o4 < 8; ++o4)
        dst[o4] = make_float4(h2c[o4 * 4 + 0], h2c[o4 * 4 + 1], h2c[o4 * 4 + 2], h2c[o4 * 4 + 3]);
    __syncthreads();

    // layer 3: this wave's 16-output chunk, full k=128 via ds_read_b128
    const int ob = sub * 16;
    float h3[16];
#pragma unroll
    for (int o = 0; o < 16; ++o) h3[o] = b3[ob + o];
    const float4* src = (const float4*)&lds_h2[lane * 132];
    for (int k4 = 0; k4 < 32; ++k4) {
        const float4 hk = src[k4];
#pragma unroll
        for (int o = 0; o < 16; ++o) {
            h3[o] += hk.x * W3[(k4 * 4 + 0) * 64 + ob + o];
            h3[o] += hk.y * W3[(k4 * 4 + 1) * 64 + ob + o];
            h3[o] += hk.z * W3[(k4 * 4 + 2) * 64 + ob + o];
            h3[o] += hk.w * W3[(k4 * 4 + 3) * 64 + ob + o];
        }
    }

    // layer 4 partial: dot of this wave's 16 relu'd h3 with its W4 chunk
    float s = 0.0f;
#pragma unroll
    for (int o = 0; o < 16; ++o) s += fmaxf(h3[o], 0.0f) * W4[ob + o];
    pr[sub * 64 + lane] = s;
    __syncthreads();

    if (sub == 0) {
        const float total = pr[lane] + pr[64 + lane] + pr[128 + lane] + pr[192 + lane] + b4[0];
        out[e] = (d <= 1.0f) ? total : 0.0f;
    }
}

extern "C" void kernel_launch(void* const* d_in, const int* in_sizes, int n_in,
                              void* d_out, int out_size, void* d_ws, size_t ws_size,
                              hipStream_t stream) {
    const float* states = (const float*)d_in[0];
    const float* W1 = (const float*)d_in[1];
    const float* b1 = (const float*)d_in[2];
    const float* W2 = (const float*)d_in[3];
    const float* b2 = (const float*)d_in[4];
    const float* W3 = (const float*)d_in[5];
    const float* b3 = (const float*)d_in[6];
    const float* W4 = (const float*)d_in[7];
    const float* b4 = (const float*)d_in[8];

    int* idx = (int*)d_ws;
    float* dist = (float*)((char*)d_ws + (size_t)N_AGENTS * TOPK * sizeof(int));

    topk_kernel<<<N_AGENTS, 256, 0, stream>>>(states, idx, dist);
    mlp_kernel<<<(N_AGENTS * TOPK) / 64, 256, 0, stream>>>(
        states, idx, dist, W1, b1, W2, b2, W3, b3, W4, b4, (float*)d_out);
}

// Round 4
// 101.009 us; speedup vs baseline: 2.1199x; 1.5733x over previous
//
#include <hip/hip_runtime.h>
#include <stdint.h>

#define N_AGENTS 4096
#define TOPK 12
#define EPSF 1e-4f

typedef unsigned long long u64;
typedef _Float16 half8 __attribute__((ext_vector_type(8)));
typedef float floatx4 __attribute__((ext_vector_type(4)));

static __device__ __forceinline__ u64 umin64(u64 a, u64 b) { return a < b ? a : b; }

// Cross-lane xor-exchange of a u64. J<=16 via ds_swizzle (BitMode, within
// 32-lane halves); J=32 via ds_bpermute (full wave64).
template <int J>
static __device__ __forceinline__ u64 xswap64(u64 v, int bpaddr) {
    int lo = (int)(unsigned int)(v & 0xffffffffULL);
    int hi = (int)(unsigned int)(v >> 32);
    int nlo, nhi;
    if constexpr (J == 32) {
        nlo = __builtin_amdgcn_ds_bpermute(bpaddr, lo);
        nhi = __builtin_amdgcn_ds_bpermute(bpaddr, hi);
    } else {
        constexpr int imm = 0x1F | (J << 10);
        nlo = __builtin_amdgcn_ds_swizzle(lo, imm);
        nhi = __builtin_amdgcn_ds_swizzle(hi, imm);
    }
    return ((u64)(unsigned int)nhi << 32) | (unsigned int)nlo;
}

template <int K, int J>
static __device__ __forceinline__ u64 ce_stage(u64 v, int lane, int bpaddr) {
    const u64 o = xswap64<J>(v, bpaddr);
    const bool up = (K == 64) ? true : ((lane & K) == 0);
    const bool keepmin = (((lane & J) == 0) == up);
    const bool lt = v < o;
    const u64 mn = lt ? v : o;
    const u64 mx = lt ? o : v;
    return keepmin ? mn : mx;
}

// Full ascending bitonic sort of one value per lane across 64 lanes.
static __device__ __forceinline__ u64 bitonic64(u64 v, int lane, int bpaddr) {
    v = ce_stage<2, 1>(v, lane, bpaddr);
    v = ce_stage<4, 2>(v, lane, bpaddr);
    v = ce_stage<4, 1>(v, lane, bpaddr);
    v = ce_stage<8, 4>(v, lane, bpaddr);
    v = ce_stage<8, 2>(v, lane, bpaddr);
    v = ce_stage<8, 1>(v, lane, bpaddr);
    v = ce_stage<16, 8>(v, lane, bpaddr);
    v = ce_stage<16, 4>(v, lane, bpaddr);
    v = ce_stage<16, 2>(v, lane, bpaddr);
    v = ce_stage<16, 1>(v, lane, bpaddr);
    v = ce_stage<32, 16>(v, lane, bpaddr);
    v = ce_stage<32, 8>(v, lane, bpaddr);
    v = ce_stage<32, 4>(v, lane, bpaddr);
    v = ce_stage<32, 2>(v, lane, bpaddr);
    v = ce_stage<32, 1>(v, lane, bpaddr);
    v = ce_stage<64, 32>(v, lane, bpaddr);
    v = ce_stage<64, 16>(v, lane, bpaddr);
    v = ce_stage<64, 8>(v, lane, bpaddr);
    v = ce_stage<64, 4>(v, lane, bpaddr);
    v = ce_stage<64, 2>(v, lane, bpaddr);
    v = ce_stage<64, 1>(v, lane, bpaddr);
    return v;
}

static __device__ __forceinline__ u64 wavemin64(u64 v, int bpaddr) {
    v = umin64(v, xswap64<1>(v, bpaddr));
    v = umin64(v, xswap64<2>(v, bpaddr));
    v = umin64(v, xswap64<4>(v, bpaddr));
    v = umin64(v, xswap64<8>(v, bpaddr));
    v = umin64(v, xswap64<16>(v, bpaddr));
    v = umin64(v, xswap64<32>(v, bpaddr));
    return v;
}

#define SURV_CAP 256

// One block (256 threads = 4 waves) per row i. Threshold-filter top-12:
// U = min over waves of (12th smallest of the wave's 64 per-thread minima)
// is a provable upper bound on the row's 12th smallest element; survivors
// (<= U, E[count]~13) are compacted and sorted once by wave 0.
__global__ __launch_bounds__(256) void topk_kernel(const float* __restrict__ states,
                                                   int* __restrict__ idx_out,
                                                   float* __restrict__ dist_out) {
    const int i = blockIdx.x;
    const int t = threadIdx.x;
    const int lane = t & 63;
    const int wv = t >> 6;
    const int bpaddr = (lane ^ 32) << 2;
    const float2* st2 = (const float2*)states;  // [j*2] = (x,y)
    const float2 me = st2[i * 2];

    u64 loc[16];
#pragma unroll
    for (int s = 0; s < 16; ++s) {
        const int j = t + s * 256;
        const float2 p = st2[j * 2];
        const float dx = me.x - p.x;
        const float dy = me.y - p.y;
        const float d2 = (dx * dx + EPSF) + (dy * dy + EPSF);  // faithful rounding
        const float d = sqrtf(d2);
        loc[s] = ((u64)__float_as_uint(d) << 32) | (unsigned int)j;
    }
    u64 lmin = loc[0];
#pragma unroll
    for (int s = 1; s < 16; ++s) lmin = umin64(lmin, loc[s]);

    __shared__ u64 wb[4];
    __shared__ u64 surv[SURV_CAP];
    __shared__ int cnt;

    const u64 sorted = bitonic64(lmin, lane, bpaddr);
    if (lane == 11) wb[wv] = sorted;
    if (t == 0) cnt = 0;
    __syncthreads();

    const u64 U = umin64(umin64(wb[0], wb[1]), umin64(wb[2], wb[3]));
#pragma unroll
    for (int s = 0; s < 16; ++s) {
        if (loc[s] <= U) {
            const int p = atomicAdd(&cnt, 1);
            if (p < SURV_CAP) surv[p] = loc[s];
        }
    }
    __syncthreads();
    const int S = cnt;

    if (S <= 64) {
        if (wv == 0) {
            u64 x = (lane < S) ? surv[lane] : ~0ULL;
            x = bitonic64(x, lane, bpaddr);
            if (lane < TOPK) {
                idx_out[i * TOPK + lane] = (int)(unsigned int)(x & 0xffffffffULL);
                dist_out[i * TOPK + lane] = __uint_as_float((unsigned int)(x >> 32));
            }
        }
    } else {
        // cold fallback (S in (64, 256]): iterative extraction by wave 0
        if (wv == 0) {
            u64 a[4];
#pragma unroll
            for (int r = 0; r < 4; ++r)
                a[r] = (lane + 64 * r < S) ? surv[lane + 64 * r] : ~0ULL;
            u64 al = umin64(umin64(a[0], a[1]), umin64(a[2], a[3]));
            for (int r = 0; r < TOPK; ++r) {
                const u64 v = wavemin64(al, bpaddr);
                if (lane == 0) {
                    idx_out[i * TOPK + r] = (int)(unsigned int)(v & 0xffffffffULL);
                    dist_out[i * TOPK + r] = __uint_as_float((unsigned int)(v >> 32));
                }
                if (al == v) {
#pragma unroll
                    for (int s = 0; s < 4; ++s)
                        if (a[s] == v) a[s] = ~0ULL;
                    al = umin64(umin64(a[0], a[1]), umin64(a[2], a[3]));
                }
            }
        }
    }
}

// Convert W2 -> W2^T f16 [128][64] and W3 -> W3^T f16 [64][128] (B-operand
// layout wants 8 contiguous k per lane).
__global__ __launch_bounds__(256) void conv_kernel(const float* __restrict__ W2,
                                                   const float* __restrict__ W3,
                                                   _Float16* __restrict__ W2T,
                                                   _Float16* __restrict__ W3T) {
    const int t = blockIdx.x * 256 + threadIdx.x;
    if (t < 8192) {
        const int n = t >> 6, k = t & 63;
        W2T[n * 64 + k] = (_Float16)W2[k * 128 + n];
    } else {
        const int u = t - 8192;
        const int n = u >> 7, k = u & 127;
        W3T[n * 128 + k] = (_Float16)W3[k * 64 + n];
    }
}

// MLP: 64 edges per 256-thread block. L1 (6->64) in fp32 VALU; L2 (64->128)
// and L3 (128->64) as f16 MFMA 16x16x32 with fp32 accum; L4 (64->1) as
// per-lane dot + 16-lane swizzle reduction. B-fragments live in registers
// for the whole kernel (weights identical across blocks, L2-resident).
__global__ __launch_bounds__(256) void mlp_kernel(
    const float* __restrict__ states,
    const int* __restrict__ idx_in,
    const float* __restrict__ dist_in,
    const float* __restrict__ W1, const float* __restrict__ b1,
    const float* __restrict__ b2, const float* __restrict__ b3,
    const float* __restrict__ W4, const float* __restrict__ b4,
    const _Float16* __restrict__ W2T, const _Float16* __restrict__ W3T,
    float* __restrict__ out) {
    __shared__ __align__(16) _Float16 h1s[64 * 72];    // [m=edge][k], pad 8
    __shared__ __align__(16) _Float16 h2s[64 * 136];   // [m=edge][k], pad 8
    __shared__ float partial[4 * 64];

    const int t = threadIdx.x;
    const int lane = t & 63;
    const int wv = __builtin_amdgcn_readfirstlane(t >> 6);
    const int quad = lane >> 4;
    const int l15 = lane & 15;
    const int e0 = blockIdx.x * 64;

    // B-fragment preload (registers for whole kernel)
    half8 b2f[2][2], b3f[4];
#pragma unroll
    for (int ks = 0; ks < 2; ++ks)
#pragma unroll
        for (int nt = 0; nt < 2; ++nt) {
            const int n = wv * 32 + nt * 16 + l15;
            b2f[ks][nt] = *(const half8*)(W2T + n * 64 + ks * 32 + quad * 8);
        }
#pragma unroll
    for (int ks = 0; ks < 4; ++ks) {
        const int n = wv * 16 + l15;
        b3f[ks] = *(const half8*)(W3T + n * 128 + ks * 32 + quad * 8);
    }

    // ---- layer 1 (fp32): edge = lane, this wave computes o in [16wv,16wv+16)
    {
        const int e = e0 + lane;
        const int i = e / TOPK;
        const int j = idx_in[e];
        const float d = dist_in[e];
        float feat[6];
#pragma unroll
        for (int c = 0; c < 4; ++c) feat[c] = states[i * 4 + c] - states[j * 4 + c];
        feat[4] = (i == j) ? 1.0f : 0.0f;
        feat[5] = d - 0.1f;

        _Float16 h1v[16];
#pragma unroll
        for (int oo = 0; oo < 16; ++oo) {
            const int o = wv * 16 + oo;
            float acc = b1[o];
#pragma unroll
            for (int f = 0; f < 6; ++f) acc += feat[f] * W1[f * 64 + o];
            h1v[oo] = (_Float16)fmaxf(acc, 0.0f);
        }
        half8* dst = (half8*)&h1s[lane * 72 + wv * 16];
        dst[0] = *(half8*)&h1v[0];
        dst[1] = *(half8*)&h1v[8];
    }
    __syncthreads();

    // ---- layer 2 (MFMA): C[m=64][n=wv*32 .. +32]
    floatx4 acc2[4][2];
#pragma unroll
    for (int mt = 0; mt < 4; ++mt)
#pragma unroll
        for (int nt = 0; nt < 2; ++nt) acc2[mt][nt] = (floatx4){0.f, 0.f, 0.f, 0.f};
#pragma unroll
    for (int ks = 0; ks < 2; ++ks)
#pragma unroll
        for (int mt = 0; mt < 4; ++mt) {
            const half8 a = *(const half8*)&h1s[(mt * 16 + l15) * 72 + ks * 32 + quad * 8];
            acc2[mt][0] = __builtin_amdgcn_mfma_f32_16x16x32_f16(a, b2f[ks][0], acc2[mt][0], 0, 0, 0);
            acc2[mt][1] = __builtin_amdgcn_mfma_f32_16x16x32_f16(a, b2f[ks][1], acc2[mt][1], 0, 0, 0);
        }
    float bias2[2] = {b2[wv * 32 + l15], b2[wv * 32 + 16 + l15]};
#pragma unroll
    for (int mt = 0; mt < 4; ++mt)
#pragma unroll
        for (int nt = 0; nt < 2; ++nt)
#pragma unroll
            for (int r = 0; r < 4; ++r) {
                const int m = mt * 16 + quad * 4 + r;
                const int n = wv * 32 + nt * 16 + l15;
                h2s[m * 136 + n] = (_Float16)fmaxf(acc2[mt][nt][r] + bias2[nt], 0.0f);
            }
    __syncthreads();

    // ---- layer 3 (MFMA): C[m=64][n=wv*16 .. +16]
    floatx4 acc3[4];
#pragma unroll
    for (int mt = 0; mt < 4; ++mt) acc3[mt] = (floatx4){0.f, 0.f, 0.f, 0.f};
#pragma unroll
    for (int ks = 0; ks < 4; ++ks)
#pragma unroll
        for (int mt = 0; mt < 4; ++mt) {
            const half8 a = *(const half8*)&h2s[(mt * 16 + l15) * 136 + ks * 32 + quad * 8];
            acc3[mt] = __builtin_amdgcn_mfma_f32_16x16x32_f16(a, b3f[ks], acc3[mt], 0, 0, 0);
        }

    // ---- layer 4: per-lane relu+dot, reduce over the 16 n's in each quad
    const int n3 = wv * 16 + l15;
    const float bias3 = b3[n3];
    const float w4v = W4[n3];
#pragma unroll
    for (int mt = 0; mt < 4; ++mt)
#pragma unroll
        for (int r = 0; r < 4; ++r) {
            float v = fmaxf(acc3[mt][r] + bias3, 0.0f) * w4v;
            v += __int_as_float(__builtin_amdgcn_ds_swizzle(__float_as_int(v), 0x041F));
            v += __int_as_float(__builtin_amdgcn_ds_swizzle(__float_as_int(v), 0x081F));
            v += __int_as_float(__builtin_amdgcn_ds_swizzle(__float_as_int(v), 0x101F));
            v += __int_as_float(__builtin_amdgcn_ds_swizzle(__float_as_int(v), 0x201F));
            if (l15 == 0) partial[wv * 64 + mt * 16 + quad * 4 + r] = v;
        }
    __syncthreads();

    if (t < 64) {
        const float s = partial[t] + partial[64 + t] + partial[128 + t] + partial[192 + t] + b4[0];
        const float d = dist_in[e0 + t];
        out[e0 + t] = (d <= 1.0f) ? s : 0.0f;
    }
}

extern "C" void kernel_launch(void* const* d_in, const int* in_sizes, int n_in,
                              void* d_out, int out_size, void* d_ws, size_t ws_size,
                              hipStream_t stream) {
    const float* states = (const float*)d_in[0];
    const float* W1 = (const float*)d_in[1];
    const float* b1 = (const float*)d_in[2];
    const float* W2 = (const float*)d_in[3];
    const float* b2 = (const float*)d_in[4];
    const float* W3 = (const float*)d_in[5];
    const float* b3 = (const float*)d_in[6];
    const float* W4 = (const float*)d_in[7];
    const float* b4 = (const float*)d_in[8];

    char* ws = (char*)d_ws;
    int* idx = (int*)ws;                                          // 192 KB
    float* dist = (float*)(ws + 192 * 1024);                      // 192 KB
    _Float16* W2T = (_Float16*)(ws + 384 * 1024);                 // 16 KB
    _Float16* W3T = (_Float16*)(ws + 400 * 1024);                 // 16 KB

    conv_kernel<<<64, 256, 0, stream>>>(W2, W3, W2T, W3T);
    topk_kernel<<<N_AGENTS, 256, 0, stream>>>(states, idx, dist);
    mlp_kernel<<<(N_AGENTS * TOPK) / 64, 256, 0, stream>>>(
        states, idx, dist, W1, b1, b2, b3, W4, b4, W2T, W3T, (float*)d_out);
}

// Round 5
// 98.346 us; speedup vs baseline: 2.1773x; 1.0271x over previous
//
#include <hip/hip_runtime.h>
#include <stdint.h>

#define N_AGENTS 4096
#define TOPK 12
#define EPSF 1e-4f

typedef unsigned long long u64;
typedef _Float16 half8 __attribute__((ext_vector_type(8)));
typedef float floatx4 __attribute__((ext_vector_type(4)));

static __device__ __forceinline__ u64 umin64(u64 a, u64 b) { return a < b ? a : b; }

// Cross-lane xor-exchange of a u64. J<=16 via ds_swizzle (BitMode, within
// 32-lane halves); J=32 via ds_bpermute (full wave64).
template <int J>
static __device__ __forceinline__ u64 xswap64(u64 v, int bpaddr) {
    int lo = (int)(unsigned int)(v & 0xffffffffULL);
    int hi = (int)(unsigned int)(v >> 32);
    int nlo, nhi;
    if constexpr (J == 32) {
        nlo = __builtin_amdgcn_ds_bpermute(bpaddr, lo);
        nhi = __builtin_amdgcn_ds_bpermute(bpaddr, hi);
    } else {
        constexpr int imm = 0x1F | (J << 10);
        nlo = __builtin_amdgcn_ds_swizzle(lo, imm);
        nhi = __builtin_amdgcn_ds_swizzle(hi, imm);
    }
    return ((u64)(unsigned int)nhi << 32) | (unsigned int)nlo;
}

template <int K, int J>
static __device__ __forceinline__ u64 ce_stage(u64 v, int lane, int bpaddr) {
    const u64 o = xswap64<J>(v, bpaddr);
    const bool up = (K == 64) ? true : ((lane & K) == 0);
    const bool keepmin = (((lane & J) == 0) == up);
    const bool lt = v < o;
    const u64 mn = lt ? v : o;
    const u64 mx = lt ? o : v;
    return keepmin ? mn : mx;
}

// Full ascending bitonic sort of one value per lane across 64 lanes.
static __device__ __forceinline__ u64 bitonic64(u64 v, int lane, int bpaddr) {
    v = ce_stage<2, 1>(v, lane, bpaddr);
    v = ce_stage<4, 2>(v, lane, bpaddr);
    v = ce_stage<4, 1>(v, lane, bpaddr);
    v = ce_stage<8, 4>(v, lane, bpaddr);
    v = ce_stage<8, 2>(v, lane, bpaddr);
    v = ce_stage<8, 1>(v, lane, bpaddr);
    v = ce_stage<16, 8>(v, lane, bpaddr);
    v = ce_stage<16, 4>(v, lane, bpaddr);
    v = ce_stage<16, 2>(v, lane, bpaddr);
    v = ce_stage<16, 1>(v, lane, bpaddr);
    v = ce_stage<32, 16>(v, lane, bpaddr);
    v = ce_stage<32, 8>(v, lane, bpaddr);
    v = ce_stage<32, 4>(v, lane, bpaddr);
    v = ce_stage<32, 2>(v, lane, bpaddr);
    v = ce_stage<32, 1>(v, lane, bpaddr);
    v = ce_stage<64, 32>(v, lane, bpaddr);
    v = ce_stage<64, 16>(v, lane, bpaddr);
    v = ce_stage<64, 8>(v, lane, bpaddr);
    v = ce_stage<64, 4>(v, lane, bpaddr);
    v = ce_stage<64, 2>(v, lane, bpaddr);
    v = ce_stage<64, 1>(v, lane, bpaddr);
    return v;
}

static __device__ __forceinline__ u64 wavemin64(u64 v, int bpaddr) {
    v = umin64(v, xswap64<1>(v, bpaddr));
    v = umin64(v, xswap64<2>(v, bpaddr));
    v = umin64(v, xswap64<4>(v, bpaddr));
    v = umin64(v, xswap64<8>(v, bpaddr));
    v = umin64(v, xswap64<16>(v, bpaddr));
    v = umin64(v, xswap64<32>(v, bpaddr));
    return v;
}

#define SURV_CAP 256

// One block (256 threads = 4 waves) per row i. Threshold-filter top-12:
// U = min over waves of (12th smallest of the wave's 64 per-thread minima)
// is a provable upper bound on the row's 12th smallest element; survivors
// (<= U, E[count]~13) are compacted and sorted once by wave 0.
__global__ __launch_bounds__(256) void topk_kernel(const float* __restrict__ states,
                                                   int* __restrict__ idx_out,
                                                   float* __restrict__ dist_out) {
    const int i = blockIdx.x;
    const int t = threadIdx.x;
    const int lane = t & 63;
    const int wv = t >> 6;
    const int bpaddr = (lane ^ 32) << 2;
    const float2* st2 = (const float2*)states;  // [j*2] = (x,y)
    const float2 me = st2[i * 2];

    u64 loc[16];
#pragma unroll
    for (int s = 0; s < 16; ++s) {
        const int j = t + s * 256;
        const float2 p = st2[j * 2];
        const float dx = me.x - p.x;
        const float dy = me.y - p.y;
        const float d2 = (dx * dx + EPSF) + (dy * dy + EPSF);  // faithful rounding
        const float d = sqrtf(d2);
        loc[s] = ((u64)__float_as_uint(d) << 32) | (unsigned int)j;
    }
    u64 lmin = loc[0];
#pragma unroll
    for (int s = 1; s < 16; ++s) lmin = umin64(lmin, loc[s]);

    __shared__ u64 wb[4];
    __shared__ u64 surv[SURV_CAP];
    __shared__ int cnt;

    const u64 sorted = bitonic64(lmin, lane, bpaddr);
    if (lane == 11) wb[wv] = sorted;
    if (t == 0) cnt = 0;
    __syncthreads();

    const u64 U = umin64(umin64(wb[0], wb[1]), umin64(wb[2], wb[3]));
#pragma unroll
    for (int s = 0; s < 16; ++s) {
        if (loc[s] <= U) {
            const int p = atomicAdd(&cnt, 1);
            if (p < SURV_CAP) surv[p] = loc[s];
        }
    }
    __syncthreads();
    const int S = cnt;

    if (S <= 64) {
        if (wv == 0) {
            u64 x = (lane < S) ? surv[lane] : ~0ULL;
            x = bitonic64(x, lane, bpaddr);
            if (lane < TOPK) {
                idx_out[i * TOPK + lane] = (int)(unsigned int)(x & 0xffffffffULL);
                dist_out[i * TOPK + lane] = __uint_as_float((unsigned int)(x >> 32));
            }
        }
    } else {
        // cold fallback (S in (64, 256]): iterative extraction by wave 0
        if (wv == 0) {
            u64 a[4];
#pragma unroll
            for (int r = 0; r < 4; ++r)
                a[r] = (lane + 64 * r < S) ? surv[lane + 64 * r] : ~0ULL;
            u64 al = umin64(umin64(a[0], a[1]), umin64(a[2], a[3]));
            for (int r = 0; r < TOPK; ++r) {
                const u64 v = wavemin64(al, bpaddr);
                if (lane == 0) {
                    idx_out[i * TOPK + r] = (int)(unsigned int)(v & 0xffffffffULL);
                    dist_out[i * TOPK + r] = __uint_as_float((unsigned int)(v >> 32));
                }
                if (al == v) {
#pragma unroll
                    for (int s = 0; s < 4; ++s)
                        if (a[s] == v) a[s] = ~0ULL;
                    al = umin64(umin64(a[0], a[1]), umin64(a[2], a[3]));
                }
            }
        }
    }
}

// MLP: 64 edges per 256-thread block. L1 (6->64) in fp32 VALU; L2 (64->128)
// and L3 (128->64) as f16 MFMA 16x16x32 with fp32 accum; L4 (64->1) as
// per-lane dot + 16-lane swizzle reduction. B-fragments are gathered straight
// from the fp32 W2/W3 with inline f32->f16 cvt (no separate transpose kernel);
// weights are L2-resident so the strided gathers are cheap and overlap L1.
__global__ __launch_bounds__(256) void mlp_kernel(
    const float* __restrict__ states,
    const int* __restrict__ idx_in,
    const float* __restrict__ dist_in,
    const float* __restrict__ W1, const float* __restrict__ b1,
    const float* __restrict__ W2, const float* __restrict__ b2,
    const float* __restrict__ W3, const float* __restrict__ b3,
    const float* __restrict__ W4, const float* __restrict__ b4,
    float* __restrict__ out) {
    __shared__ __align__(16) _Float16 h1s[64 * 72];    // [m=edge][k], pad 8
    __shared__ __align__(16) _Float16 h2s[64 * 136];   // [m=edge][k], pad 8
    __shared__ float partial[4 * 64];

    const int t = threadIdx.x;
    const int lane = t & 63;
    const int wv = __builtin_amdgcn_readfirstlane(t >> 6);
    const int quad = lane >> 4;
    const int l15 = lane & 15;
    const int e0 = blockIdx.x * 64;

    // B-fragment construction from fp32 weights (registers for whole kernel).
    // B layout for 16x16x32: lane n = l15 (+16*quad? no: n=lane&15), holds 8
    // consecutive k at k = ks*32 + quad*8. W2 is [k][n=128], W3 is [k][n=64].
    half8 b2f[2][2], b3f[4];
#pragma unroll
    for (int ks = 0; ks < 2; ++ks)
#pragma unroll
        for (int nt = 0; nt < 2; ++nt) {
            const int n = wv * 32 + nt * 16 + l15;
            const float* p = W2 + (ks * 32 + quad * 8) * 128 + n;
            half8 f;
#pragma unroll
            for (int jj = 0; jj < 8; ++jj) f[jj] = (_Float16)p[jj * 128];
            b2f[ks][nt] = f;
        }
    const int n3 = wv * 16 + l15;
#pragma unroll
    for (int ks = 0; ks < 4; ++ks) {
        const float* p = W3 + (ks * 32 + quad * 8) * 64 + n3;
        half8 f;
#pragma unroll
        for (int jj = 0; jj < 8; ++jj) f[jj] = (_Float16)p[jj * 64];
        b3f[ks] = f;
    }

    // ---- layer 1 (fp32): edge = lane, this wave computes o in [16wv,16wv+16)
    {
        const int e = e0 + lane;
        const int i = e / TOPK;
        const int j = idx_in[e];
        const float d = dist_in[e];
        float feat[6];
#pragma unroll
        for (int c = 0; c < 4; ++c) feat[c] = states[i * 4 + c] - states[j * 4 + c];
        feat[4] = (i == j) ? 1.0f : 0.0f;
        feat[5] = d - 0.1f;

        _Float16 h1v[16];
#pragma unroll
        for (int oo = 0; oo < 16; ++oo) {
            const int o = wv * 16 + oo;
            float acc = b1[o];
#pragma unroll
            for (int f = 0; f < 6; ++f) acc += feat[f] * W1[f * 64 + o];
            h1v[oo] = (_Float16)fmaxf(acc, 0.0f);
        }
        half8* dst = (half8*)&h1s[lane * 72 + wv * 16];
        dst[0] = *(half8*)&h1v[0];
        dst[1] = *(half8*)&h1v[8];
    }
    __syncthreads();

    // ---- layer 2 (MFMA): C[m=64][n=wv*32 .. +32]
    floatx4 acc2[4][2];
#pragma unroll
    for (int mt = 0; mt < 4; ++mt)
#pragma unroll
        for (int nt = 0; nt < 2; ++nt) acc2[mt][nt] = (floatx4){0.f, 0.f, 0.f, 0.f};
#pragma unroll
    for (int ks = 0; ks < 2; ++ks)
#pragma unroll
        for (int mt = 0; mt < 4; ++mt) {
            const half8 a = *(const half8*)&h1s[(mt * 16 + l15) * 72 + ks * 32 + quad * 8];
            acc2[mt][0] = __builtin_amdgcn_mfma_f32_16x16x32_f16(a, b2f[ks][0], acc2[mt][0], 0, 0, 0);
            acc2[mt][1] = __builtin_amdgcn_mfma_f32_16x16x32_f16(a, b2f[ks][1], acc2[mt][1], 0, 0, 0);
        }
    float bias2[2] = {b2[wv * 32 + l15], b2[wv * 32 + 16 + l15]};
#pragma unroll
    for (int mt = 0; mt < 4; ++mt)
#pragma unroll
        for (int nt = 0; nt < 2; ++nt)
#pragma unroll
            for (int r = 0; r < 4; ++r) {
                const int m = mt * 16 + quad * 4 + r;
                const int n = wv * 32 + nt * 16 + l15;
                h2s[m * 136 + n] = (_Float16)fmaxf(acc2[mt][nt][r] + bias2[nt], 0.0f);
            }
    __syncthreads();

    // ---- layer 3 (MFMA): C[m=64][n=wv*16 .. +16]
    floatx4 acc3[4];
#pragma unroll
    for (int mt = 0; mt < 4; ++mt) acc3[mt] = (floatx4){0.f, 0.f, 0.f, 0.f};
#pragma unroll
    for (int ks = 0; ks < 4; ++ks)
#pragma unroll
        for (int mt = 0; mt < 4; ++mt) {
            const half8 a = *(const half8*)&h2s[(mt * 16 + l15) * 136 + ks * 32 + quad * 8];
            acc3[mt] = __builtin_amdgcn_mfma_f32_16x16x32_f16(a, b3f[ks], acc3[mt], 0, 0, 0);
        }

    // ---- layer 4: per-lane relu+dot, reduce over the 16 n's in each quad
    const float bias3 = b3[n3];
    const float w4v = W4[n3];
#pragma unroll
    for (int mt = 0; mt < 4; ++mt)
#pragma unroll
        for (int r = 0; r < 4; ++r) {
            float v = fmaxf(acc3[mt][r] + bias3, 0.0f) * w4v;
            v += __int_as_float(__builtin_amdgcn_ds_swizzle(__float_as_int(v), 0x041F));
            v += __int_as_float(__builtin_amdgcn_ds_swizzle(__float_as_int(v), 0x081F));
            v += __int_as_float(__builtin_amdgcn_ds_swizzle(__float_as_int(v), 0x101F));
            v += __int_as_float(__builtin_amdgcn_ds_swizzle(__float_as_int(v), 0x201F));
            if (l15 == 0) partial[wv * 64 + mt * 16 + quad * 4 + r] = v;
        }
    __syncthreads();

    if (t < 64) {
        const float s = partial[t] + partial[64 + t] + partial[128 + t] + partial[192 + t] + b4[0];
        const float d = dist_in[e0 + t];
        out[e0 + t] = (d <= 1.0f) ? s : 0.0f;
    }
}

extern "C" void kernel_launch(void* const* d_in, const int* in_sizes, int n_in,
                              void* d_out, int out_size, void* d_ws, size_t ws_size,
                              hipStream_t stream) {
    const float* states = (const float*)d_in[0];
    const float* W1 = (const float*)d_in[1];
    const float* b1 = (const float*)d_in[2];
    const float* W2 = (const float*)d_in[3];
    const float* b2 = (const float*)d_in[4];
    const float* W3 = (const float*)d_in[5];
    const float* b3 = (const float*)d_in[6];
    const float* W4 = (const float*)d_in[7];
    const float* b4 = (const float*)d_in[8];

    char* ws = (char*)d_ws;
    int* idx = (int*)ws;                      // 192 KB
    float* dist = (float*)(ws + 192 * 1024);  // 192 KB

    topk_kernel<<<N_AGENTS, 256, 0, stream>>>(states, idx, dist);
    mlp_kernel<<<(N_AGENTS * TOPK) / 64, 256, 0, stream>>>(
        states, idx, dist, W1, b1, W2, b2, W3, b3, W4, b4, (float*)d_out);
}

// Round 6
// 93.111 us; speedup vs baseline: 2.2997x; 1.0562x over previous
//
#include <hip/hip_runtime.h>
#include <stdint.h>

#define N_AGENTS 4096
#define TOPK 12
#define EPSF 1e-4f

typedef unsigned long long u64;
typedef _Float16 half8 __attribute__((ext_vector_type(8)));
typedef float floatx4 __attribute__((ext_vector_type(4)));

static __device__ __forceinline__ u64 umin64(u64 a, u64 b) { return a < b ? a : b; }

// ---- 32-bit cross-lane xor exchange (J<=16 swizzle, J=32 bpermute) ----
template <int J>
static __device__ __forceinline__ uint32_t xswap32(uint32_t v, int bpaddr) {
    if constexpr (J == 32) {
        return (uint32_t)__builtin_amdgcn_ds_bpermute(bpaddr, (int)v);
    } else {
        constexpr int imm = 0x1F | (J << 10);
        return (uint32_t)__builtin_amdgcn_ds_swizzle((int)v, imm);
    }
}

template <int K, int J>
static __device__ __forceinline__ uint32_t ce_stage32(uint32_t v, int lane, int bpaddr) {
    const uint32_t o = xswap32<J>(v, bpaddr);
    const bool up = (K == 64) ? true : ((lane & K) == 0);
    const bool keepmin = (((lane & J) == 0) == up);
    const uint32_t mn = v < o ? v : o;
    const uint32_t mx = v < o ? o : v;
    return keepmin ? mn : mx;
}

// Ascending bitonic sort of one uint32 per lane across 64 lanes (order bound
// only; ties don't matter here).
static __device__ __forceinline__ uint32_t bitonic64_u32(uint32_t v, int lane, int bpaddr) {
    v = ce_stage32<2, 1>(v, lane, bpaddr);
    v = ce_stage32<4, 2>(v, lane, bpaddr);
    v = ce_stage32<4, 1>(v, lane, bpaddr);
    v = ce_stage32<8, 4>(v, lane, bpaddr);
    v = ce_stage32<8, 2>(v, lane, bpaddr);
    v = ce_stage32<8, 1>(v, lane, bpaddr);
    v = ce_stage32<16, 8>(v, lane, bpaddr);
    v = ce_stage32<16, 4>(v, lane, bpaddr);
    v = ce_stage32<16, 2>(v, lane, bpaddr);
    v = ce_stage32<16, 1>(v, lane, bpaddr);
    v = ce_stage32<32, 16>(v, lane, bpaddr);
    v = ce_stage32<32, 8>(v, lane, bpaddr);
    v = ce_stage32<32, 4>(v, lane, bpaddr);
    v = ce_stage32<32, 2>(v, lane, bpaddr);
    v = ce_stage32<32, 1>(v, lane, bpaddr);
    v = ce_stage32<64, 32>(v, lane, bpaddr);
    v = ce_stage32<64, 16>(v, lane, bpaddr);
    v = ce_stage32<64, 8>(v, lane, bpaddr);
    v = ce_stage32<64, 4>(v, lane, bpaddr);
    v = ce_stage32<64, 2>(v, lane, bpaddr);
    v = ce_stage32<64, 1>(v, lane, bpaddr);
    return v;
}

// ---- 64-bit variants (exact final sort: key = (dist_bits<<32)|j) ----
template <int J>
static __device__ __forceinline__ u64 xswap64(u64 v, int bpaddr) {
    int lo = (int)(unsigned int)(v & 0xffffffffULL);
    int hi = (int)(unsigned int)(v >> 32);
    int nlo, nhi;
    if constexpr (J == 32) {
        nlo = __builtin_amdgcn_ds_bpermute(bpaddr, lo);
        nhi = __builtin_amdgcn_ds_bpermute(bpaddr, hi);
    } else {
        constexpr int imm = 0x1F | (J << 10);
        nlo = __builtin_amdgcn_ds_swizzle(lo, imm);
        nhi = __builtin_amdgcn_ds_swizzle(hi, imm);
    }
    return ((u64)(unsigned int)nhi << 32) | (unsigned int)nlo;
}

template <int K, int J>
static __device__ __forceinline__ u64 ce_stage(u64 v, int lane, int bpaddr) {
    const u64 o = xswap64<J>(v, bpaddr);
    const bool up = (K == 64) ? true : ((lane & K) == 0);
    const bool keepmin = (((lane & J) == 0) == up);
    const bool lt = v < o;
    const u64 mn = lt ? v : o;
    const u64 mx = lt ? o : v;
    return keepmin ? mn : mx;
}

static __device__ __forceinline__ u64 bitonic64(u64 v, int lane, int bpaddr) {
    v = ce_stage<2, 1>(v, lane, bpaddr);
    v = ce_stage<4, 2>(v, lane, bpaddr);
    v = ce_stage<4, 1>(v, lane, bpaddr);
    v = ce_stage<8, 4>(v, lane, bpaddr);
    v = ce_stage<8, 2>(v, lane, bpaddr);
    v = ce_stage<8, 1>(v, lane, bpaddr);
    v = ce_stage<16, 8>(v, lane, bpaddr);
    v = ce_stage<16, 4>(v, lane, bpaddr);
    v = ce_stage<16, 2>(v, lane, bpaddr);
    v = ce_stage<16, 1>(v, lane, bpaddr);
    v = ce_stage<32, 16>(v, lane, bpaddr);
    v = ce_stage<32, 8>(v, lane, bpaddr);
    v = ce_stage<32, 4>(v, lane, bpaddr);
    v = ce_stage<32, 2>(v, lane, bpaddr);
    v = ce_stage<32, 1>(v, lane, bpaddr);
    v = ce_stage<64, 32>(v, lane, bpaddr);
    v = ce_stage<64, 16>(v, lane, bpaddr);
    v = ce_stage<64, 8>(v, lane, bpaddr);
    v = ce_stage<64, 4>(v, lane, bpaddr);
    v = ce_stage<64, 2>(v, lane, bpaddr);
    v = ce_stage<64, 1>(v, lane, bpaddr);
    return v;
}

static __device__ __forceinline__ u64 wavemin64(u64 v, int bpaddr) {
    v = umin64(v, xswap64<1>(v, bpaddr));
    v = umin64(v, xswap64<2>(v, bpaddr));
    v = umin64(v, xswap64<4>(v, bpaddr));
    v = umin64(v, xswap64<8>(v, bpaddr));
    v = umin64(v, xswap64<16>(v, bpaddr));
    v = umin64(v, xswap64<32>(v, bpaddr));
    return v;
}

#define SURV_CAP 256

// One block (256 threads = 4 waves) per row i. Threshold-filter top-12.
// Stage 1 runs entirely on 32-bit distance bits (positive floats: uint order
// == float order); exactness (dist,index) only matters in the final sort of
// ~13 survivors, which stays 64-bit.
__global__ __launch_bounds__(256) void topk_kernel(const float* __restrict__ states,
                                                   int* __restrict__ idx_out,
                                                   float* __restrict__ dist_out) {
    const int i = blockIdx.x;
    const int t = threadIdx.x;
    const int lane = t & 63;
    const int wv = t >> 6;
    const int bpaddr = (lane ^ 32) << 2;
    const float2* st2 = (const float2*)states;  // [j*2] = (x,y)
    const float2 me = st2[i * 2];

    uint32_t d32[16];
#pragma unroll
    for (int s = 0; s < 16; ++s) {
        const int j = t + s * 256;
        const float2 p = st2[j * 2];
        const float dx = me.x - p.x;
        const float dy = me.y - p.y;
        const float d2 = (dx * dx + EPSF) + (dy * dy + EPSF);  // faithful rounding
        d32[s] = __float_as_uint(sqrtf(d2));
    }
    uint32_t lmin = d32[0];
#pragma unroll
    for (int s = 1; s < 16; ++s) lmin = d32[s] < lmin ? d32[s] : lmin;

    __shared__ uint32_t wb[4];
    __shared__ u64 surv[SURV_CAP];
    __shared__ int cnt;

    // 12th smallest of this wave's 64 lane-minima = provable upper bound on
    // the row's 12th smallest distance (the 12 smallest lane-minima are
    // themselves 12 distinct candidates <= it).
    const uint32_t sorted = bitonic64_u32(lmin, lane, bpaddr);
    if (lane == 11) wb[wv] = sorted;
    if (t == 0) cnt = 0;
    __syncthreads();

    uint32_t U = wb[0];
    U = wb[1] < U ? wb[1] : U;
    U = wb[2] < U ? wb[2] : U;
    U = wb[3] < U ? wb[3] : U;

#pragma unroll
    for (int s = 0; s < 16; ++s) {
        if (d32[s] <= U) {  // include ties; exact order fixed in final sort
            const int p = atomicAdd(&cnt, 1);
            if (p < SURV_CAP)
                surv[p] = ((u64)d32[s] << 32) | (unsigned int)(t + s * 256);
        }
    }
    __syncthreads();
    const int S = cnt;

    if (S <= 64) {
        if (wv == 0) {
            u64 x = (lane < S) ? surv[lane] : ~0ULL;
            x = bitonic64(x, lane, bpaddr);
            if (lane < TOPK) {
                idx_out[i * TOPK + lane] = (int)(unsigned int)(x & 0xffffffffULL);
                dist_out[i * TOPK + lane] = __uint_as_float((unsigned int)(x >> 32));
            }
        }
    } else {
        // cold fallback (S in (64, 256]): iterative extraction by wave 0
        if (wv == 0) {
            u64 a[4];
#pragma unroll
            for (int r = 0; r < 4; ++r)
                a[r] = (lane + 64 * r < S) ? surv[lane + 64 * r] : ~0ULL;
            u64 al = umin64(umin64(a[0], a[1]), umin64(a[2], a[3]));
            for (int r = 0; r < TOPK; ++r) {
                const u64 v = wavemin64(al, bpaddr);
                if (lane == 0) {
                    idx_out[i * TOPK + r] = (int)(unsigned int)(v & 0xffffffffULL);
                    dist_out[i * TOPK + r] = __uint_as_float((unsigned int)(v >> 32));
                }
                if (al == v) {
#pragma unroll
                    for (int s = 0; s < 4; ++s)
                        if (a[s] == v) a[s] = ~0ULL;
                    al = umin64(umin64(a[0], a[1]), umin64(a[2], a[3]));
                }
            }
        }
    }
}

// MLP: 64 edges per 256-thread block. L1 (6->64) in fp32 VALU; L2 (64->128)
// and L3 (128->64) as f16 MFMA 16x16x32 with fp32 accum; L4 (64->1) as
// per-lane dot + 16-lane swizzle reduction. B-fragments are gathered straight
// from the fp32 W2/W3 with inline f32->f16 cvt (weights L2-resident).
__global__ __launch_bounds__(256) void mlp_kernel(
    const float* __restrict__ states,
    const int* __restrict__ idx_in,
    const float* __restrict__ dist_in,
    const float* __restrict__ W1, const float* __restrict__ b1,
    const float* __restrict__ W2, const float* __restrict__ b2,
    const float* __restrict__ W3, const float* __restrict__ b3,
    const float* __restrict__ W4, const float* __restrict__ b4,
    float* __restrict__ out) {
    __shared__ __align__(16) _Float16 h1s[64 * 72];    // [m=edge][k], pad 8
    __shared__ __align__(16) _Float16 h2s[64 * 136];   // [m=edge][k], pad 8
    __shared__ float partial[4 * 64];

    const int t = threadIdx.x;
    const int lane = t & 63;
    const int wv = __builtin_amdgcn_readfirstlane(t >> 6);
    const int quad = lane >> 4;
    const int l15 = lane & 15;
    const int e0 = blockIdx.x * 64;

    // B-fragment construction from fp32 weights (registers for whole kernel).
    // 16x16x32 B layout: lane n = lane&15, 8 consecutive k at ks*32 + quad*8.
    half8 b2f[2][2], b3f[4];
#pragma unroll
    for (int ks = 0; ks < 2; ++ks)
#pragma unroll
        for (int nt = 0; nt < 2; ++nt) {
            const int n = wv * 32 + nt * 16 + l15;
            const float* p = W2 + (ks * 32 + quad * 8) * 128 + n;
            half8 f;
#pragma unroll
            for (int jj = 0; jj < 8; ++jj) f[jj] = (_Float16)p[jj * 128];
            b2f[ks][nt] = f;
        }
    const int n3 = wv * 16 + l15;
#pragma unroll
    for (int ks = 0; ks < 4; ++ks) {
        const float* p = W3 + (ks * 32 + quad * 8) * 64 + n3;
        half8 f;
#pragma unroll
        for (int jj = 0; jj < 8; ++jj) f[jj] = (_Float16)p[jj * 64];
        b3f[ks] = f;
    }

    // ---- layer 1 (fp32): edge = lane, this wave computes o in [16wv,16wv+16)
    const float d_edge = dist_in[e0 + lane];  // wave 0's copy reused in epilogue
    {
        const int e = e0 + lane;
        const int i = e / TOPK;
        const int j = idx_in[e];
        float feat[6];
#pragma unroll
        for (int c = 0; c < 4; ++c) feat[c] = states[i * 4 + c] - states[j * 4 + c];
        feat[4] = (i == j) ? 1.0f : 0.0f;
        feat[5] = d_edge - 0.1f;

        _Float16 h1v[16];
#pragma unroll
        for (int oo = 0; oo < 16; ++oo) {
            const int o = wv * 16 + oo;
            float acc = b1[o];
#pragma unroll
            for (int f = 0; f < 6; ++f) acc += feat[f] * W1[f * 64 + o];
            h1v[oo] = (_Float16)fmaxf(acc, 0.0f);
        }
        half8* dst = (half8*)&h1s[lane * 72 + wv * 16];
        dst[0] = *(half8*)&h1v[0];
        dst[1] = *(half8*)&h1v[8];
    }
    __syncthreads();

    // ---- layer 2 (MFMA): C[m=64][n=wv*32 .. +32]
    floatx4 acc2[4][2];
#pragma unroll
    for (int mt = 0; mt < 4; ++mt)
#pragma unroll
        for (int nt = 0; nt < 2; ++nt) acc2[mt][nt] = (floatx4){0.f, 0.f, 0.f, 0.f};
#pragma unroll
    for (int ks = 0; ks < 2; ++ks)
#pragma unroll
        for (int mt = 0; mt < 4; ++mt) {
            const half8 a = *(const half8*)&h1s[(mt * 16 + l15) * 72 + ks * 32 + quad * 8];
            acc2[mt][0] = __builtin_amdgcn_mfma_f32_16x16x32_f16(a, b2f[ks][0], acc2[mt][0], 0, 0, 0);
            acc2[mt][1] = __builtin_amdgcn_mfma_f32_16x16x32_f16(a, b2f[ks][1], acc2[mt][1], 0, 0, 0);
        }
    float bias2[2] = {b2[wv * 32 + l15], b2[wv * 32 + 16 + l15]};
#pragma unroll
    for (int mt = 0; mt < 4; ++mt)
#pragma unroll
        for (int nt = 0; nt < 2; ++nt)
#pragma unroll
            for (int r = 0; r < 4; ++r) {
                const int m = mt * 16 + quad * 4 + r;
                const int n = wv * 32 + nt * 16 + l15;
                h2s[m * 136 + n] = (_Float16)fmaxf(acc2[mt][nt][r] + bias2[nt], 0.0f);
            }
    __syncthreads();

    // ---- layer 3 (MFMA): C[m=64][n=wv*16 .. +16]
    floatx4 acc3[4];
#pragma unroll
    for (int mt = 0; mt < 4; ++mt) acc3[mt] = (floatx4){0.f, 0.f, 0.f, 0.f};
#pragma unroll
    for (int ks = 0; ks < 4; ++ks)
#pragma unroll
        for (int mt = 0; mt < 4; ++mt) {
            const half8 a = *(const half8*)&h2s[(mt * 16 + l15) * 136 + ks * 32 + quad * 8];
            acc3[mt] = __builtin_amdgcn_mfma_f32_16x16x32_f16(a, b3f[ks], acc3[mt], 0, 0, 0);
        }

    // ---- layer 4: per-lane relu+dot, reduce over the 16 n's in each quad
    const float bias3 = b3[n3];
    const float w4v = W4[n3];
#pragma unroll
    for (int mt = 0; mt < 4; ++mt)
#pragma unroll
        for (int r = 0; r < 4; ++r) {
            float v = fmaxf(acc3[mt][r] + bias3, 0.0f) * w4v;
            v += __int_as_float(__builtin_amdgcn_ds_swizzle(__float_as_int(v), 0x041F));
            v += __int_as_float(__builtin_amdgcn_ds_swizzle(__float_as_int(v), 0x081F));
            v += __int_as_float(__builtin_amdgcn_ds_swizzle(__float_as_int(v), 0x101F));
            v += __int_as_float(__builtin_amdgcn_ds_swizzle(__float_as_int(v), 0x201F));
            if (l15 == 0) partial[wv * 64 + mt * 16 + quad * 4 + r] = v;
        }
    __syncthreads();

    if (t < 64) {  // wave 0: d_edge is dist_in[e0+t] already in register
        const float s = partial[t] + partial[64 + t] + partial[128 + t] + partial[192 + t] + b4[0];
        out[e0 + t] = (d_edge <= 1.0f) ? s : 0.0f;
    }
}

extern "C" void kernel_launch(void* const* d_in, const int* in_sizes, int n_in,
                              void* d_out, int out_size, void* d_ws, size_t ws_size,
                              hipStream_t stream) {
    const float* states = (const float*)d_in[0];
    const float* W1 = (const float*)d_in[1];
    const float* b1 = (const float*)d_in[2];
    const float* W2 = (const float*)d_in[3];
    const float* b2 = (const float*)d_in[4];
    const float* W3 = (const float*)d_in[5];
    const float* b3 = (const float*)d_in[6];
    const float* W4 = (const float*)d_in[7];
    const float* b4 = (const float*)d_in[8];

    char* ws = (char*)d_ws;
    int* idx = (int*)ws;                      // 192 KB
    float* dist = (float*)(ws + 192 * 1024);  // 192 KB

    topk_kernel<<<N_AGENTS, 256, 0, stream>>>(states, idx, dist);
    mlp_kernel<<<(N_AGENTS * TOPK) / 64, 256, 0, stream>>>(
        states, idx, dist, W1, b1, W2, b2, W3, b3, W4, b4, (float*)d_out);
}